// Round 1
// baseline (241.845 us; speedup 1.0000x reference)
//
#include <hip/hip_runtime.h>

#define DIM 768
#define HEADS 12
#define HD 64
#define NB 128
#define ROWS_ALL 25216   // 197*128
#define ROWS_KV  25088   // 196*128
#define NCHUNK 49
#define CKEYS 512        // keys per chunk (49*512 = 25088)

typedef __attribute__((ext_vector_type(8))) short short8;
typedef __attribute__((ext_vector_type(4))) float f32x4;

__device__ __forceinline__ unsigned short f2bf(float f) {
  union { float f; unsigned u; } a; a.f = f;
  return (unsigned short)((a.u + 0x7fffu + ((a.u >> 16) & 1u)) >> 16);
}

__device__ __forceinline__ void gload16(const void* g, void* l) {
  __builtin_amdgcn_global_load_lds(
      (__attribute__((address_space(1))) void*)g,
      (__attribute__((address_space(3))) void*)l, 16, 0, 0);
}

// ---------------- LN1 over concat([cls, x]) -> bf16 xx, plus fp32 q0 ----
__global__ __launch_bounds__(256) void ln1_kernel(
    const float* __restrict__ x, const float* __restrict__ cls,
    const float* __restrict__ g, const float* __restrict__ b,
    unsigned short* __restrict__ xx, float* __restrict__ q0f)
{
  int row = blockIdx.x * 4 + (threadIdx.x >> 6);
  int lane = threadIdx.x & 63;
  const float* src = (row < NB) ? (cls + (size_t)row * DIM)
                                : (x + (size_t)(row - NB) * DIM);
  float4 v[3];
  float s = 0.f;
#pragma unroll
  for (int i = 0; i < 3; ++i) {
    v[i] = ((const float4*)src)[lane + 64 * i];
    s += v[i].x + v[i].y + v[i].z + v[i].w;
  }
#pragma unroll
  for (int o = 32; o; o >>= 1) s += __shfl_xor(s, o);
  float mean = s * (1.f / 768.f);
  float ss = 0.f;
#pragma unroll
  for (int i = 0; i < 3; ++i) {
    float a0 = v[i].x - mean, a1 = v[i].y - mean, a2 = v[i].z - mean, a3 = v[i].w - mean;
    ss += a0 * a0 + a1 * a1 + a2 * a2 + a3 * a3;
  }
#pragma unroll
  for (int o = 32; o; o >>= 1) ss += __shfl_xor(ss, o);
  float rs = rsqrtf(ss * (1.f / 768.f) + 1e-5f);
#pragma unroll
  for (int i = 0; i < 3; ++i) {
    int c4 = lane + 64 * i;
    float4 gv = ((const float4*)g)[c4];
    float4 bv = ((const float4*)b)[c4];
    float o0 = (v[i].x - mean) * rs * gv.x + bv.x;
    float o1 = (v[i].y - mean) * rs * gv.y + bv.y;
    float o2 = (v[i].z - mean) * rs * gv.z + bv.z;
    float o3 = (v[i].w - mean) * rs * gv.w + bv.w;
    ushort4 u; u.x = f2bf(o0); u.y = f2bf(o1); u.z = f2bf(o2); u.w = f2bf(o3);
    ((ushort4*)(xx + (size_t)row * DIM))[c4] = u;
    if (row < NB) {
      float4 fo; fo.x = o0; fo.y = o1; fo.z = o2; fo.w = o3;
      ((float4*)(q0f + (size_t)row * DIM))[c4] = fo;
    }
  }
}

// ---------------- cast 5 weight matrices f32 -> bf16 (packed dst) -------
__global__ __launch_bounds__(256) void castw5(
    const float* __restrict__ s0, const float* __restrict__ s1,
    const float* __restrict__ s2, const float* __restrict__ s3,
    const float* __restrict__ s4, unsigned short* __restrict__ dst)
{
  const float* srcs[5] = { s0, s1, s2, s3, s4 };
  int w = blockIdx.y;
  const float* s = srcs[w];
  unsigned short* d = dst + (size_t)w * (DIM * DIM);
  int i = blockIdx.x * 256 + threadIdx.x;            // float4 index
  float4 v = ((const float4*)s)[i];
  ushort4 u; u.x = f2bf(v.x); u.y = f2bf(v.y); u.z = f2bf(v.z); u.w = f2bf(v.w);
  ((ushort4*)d)[i] = u;
}

// ---------------- generic C[m][n] = sum_k A[m][k]*Bt[n][k] (bf16 MFMA) --
// EPI 0: bf16 store; 1: +bias, silu(1.702), bf16 store; 2: +bias +addsrc, f32 store
template <int EPI>
__global__ __launch_bounds__(256) void gemm_bt(
    const unsigned short* __restrict__ A, const unsigned short* __restrict__ Bt,
    void* __restrict__ Cout, int M, int N, int K,
    const float* __restrict__ bias, const float* __restrict__ addsrc)
{
  __shared__ unsigned short Asm[2][128 * 32];
  __shared__ unsigned short Bsm[2][128 * 32];
  int tid = threadIdx.x, wid = tid >> 6, lane = tid & 63;
  int l15 = lane & 15, l4 = lane >> 4;
  int row0 = blockIdx.y * 128, col0 = blockIdx.x * 128;
  int srow = tid >> 2;
  int scb = (tid & 3) << 4;

  const char* Ag = (const char*)A + ((size_t)(row0 + srow) * K) * 2 + scb;
  const char* Bg = (const char*)Bt + ((size_t)(col0 + srow) * K) * 2 + scb;
  size_t rstep = (size_t)64 * K * 2;

#define STAGE(buf, kt) do {                                        \
    const char* a0 = Ag + (size_t)(kt) * 64;                       \
    const char* b0 = Bg + (size_t)(kt) * 64;                       \
    char* la = (char*)Asm[buf] + wid * 1024;                       \
    char* lb = (char*)Bsm[buf] + wid * 1024;                       \
    gload16(a0, la);                                               \
    gload16(a0 + rstep, la + 4096);                                \
    gload16(b0, lb);                                               \
    gload16(b0 + rstep, lb + 4096);                                \
  } while (0)

  f32x4 acc[4][4] = {};
  int wr = (wid >> 1) * 64, wc = (wid & 1) * 64;
  int nk = K >> 5;
  STAGE(0, 0);
  for (int t = 0; t < nk; ++t) {
    int cur = t & 1;
    if (t + 1 < nk) {
      STAGE(cur ^ 1, t + 1);
      asm volatile("s_waitcnt vmcnt(4)" ::: "memory");
    } else {
      asm volatile("s_waitcnt vmcnt(0)" ::: "memory");
    }
    __builtin_amdgcn_s_barrier();
    asm volatile("" ::: "memory");
    short8 aF[4], bF[4];
    const char* Ab = (const char*)Asm[cur];
    const char* Bb = (const char*)Bsm[cur];
#pragma unroll
    for (int m = 0; m < 4; ++m)
      aF[m] = *(const short8*)(Ab + (wr + m * 16 + l15) * 64 + l4 * 16);
#pragma unroll
    for (int n = 0; n < 4; ++n)
      bF[n] = *(const short8*)(Bb + (wc + n * 16 + l15) * 64 + l4 * 16);
#pragma unroll
    for (int m = 0; m < 4; ++m)
#pragma unroll
      for (int n = 0; n < 4; ++n)
        acc[m][n] = __builtin_amdgcn_mfma_f32_16x16x32_bf16(aF[m], bF[n], acc[m][n], 0, 0, 0);
    asm volatile("" ::: "memory");
    __builtin_amdgcn_s_barrier();
    asm volatile("" ::: "memory");
  }
#undef STAGE
#pragma unroll
  for (int m = 0; m < 4; ++m)
#pragma unroll
    for (int n = 0; n < 4; ++n)
#pragma unroll
      for (int r = 0; r < 4; ++r) {
        int rr = row0 + wr + m * 16 + l4 * 4 + r;
        int cc = col0 + wc + n * 16 + l15;
        float v = acc[m][n][r];
        if (EPI == 0) {
          ((unsigned short*)Cout)[(size_t)rr * N + cc] = f2bf(v);
        } else if (EPI == 1) {
          v += bias[cc];
          v = v / (1.f + __expf(-1.702f * v));
          ((unsigned short*)Cout)[(size_t)rr * N + cc] = f2bf(v);
        } else {
          v += bias[cc] + addsrc[(size_t)rr * N + cc];
          ((float*)Cout)[(size_t)rr * N + cc] = v;
        }
      }
}

// ---------------- flash-decode attention partials -----------------------
// block = (head, chunk); 4 waves x 32 queries; 8 key-tiles of 64
__global__ __launch_bounds__(256) void attn_partial(
    const unsigned short* __restrict__ Qb, const unsigned short* __restrict__ Kb,
    const unsigned short* __restrict__ Vt,
    float* __restrict__ Op, float* __restrict__ mp, float* __restrict__ lp)
{
  __shared__ unsigned short Klds[64 * 64];
  __shared__ unsigned short Vlds[64 * 64];
  __shared__ unsigned short Plds[4][32 * 64];
  int tid = threadIdx.x, wid = tid >> 6, lane = tid & 63;
  int l15 = lane & 15, l4 = lane >> 4;
  int head = blockIdx.x / NCHUNK, chunk = blockIdx.x % NCHUNK;

  short8 aQ[2][2];
#pragma unroll
  for (int m = 0; m < 2; ++m)
#pragma unroll
    for (int kk = 0; kk < 2; ++kk) {
      int qrow = wid * 32 + m * 16 + l15;
      aQ[m][kk] = *(const short8*)(Qb + (size_t)qrow * DIM + head * HD + kk * 32 + l4 * 8);
    }
  f32x4 accO[2][4] = {};
  float mrun[2][4], lrun[2][4];
#pragma unroll
  for (int m = 0; m < 2; ++m)
#pragma unroll
    for (int r = 0; r < 4; ++r) { mrun[m][r] = -1e30f; lrun[m][r] = 0.f; }

  int t8 = tid & 7;
  for (int kt = 0; kt < 8; ++kt) {
    int key0 = chunk * CKEYS + kt * 64;
#pragma unroll
    for (int rnd = 0; rnd < 2; ++rnd) {
      int krow = rnd * 32 + (tid >> 3);
      int sblk = t8 ^ (krow & 7);
      const char* gk = (const char*)(Kb + (size_t)(key0 + krow) * DIM + head * HD) + sblk * 16;
      gload16(gk, (char*)Klds + rnd * 4096 + wid * 1024);
      const char* gv = (const char*)(Vt + (size_t)(head * HD + krow) * ROWS_KV + key0) + sblk * 16;
      gload16(gv, (char*)Vlds + rnd * 4096 + wid * 1024);
    }
    asm volatile("s_waitcnt vmcnt(0)" ::: "memory");
    __builtin_amdgcn_s_barrier();
    asm volatile("" ::: "memory");

    // S = Q K^T
    f32x4 sc[2][4] = {};
#pragma unroll
    for (int kk = 0; kk < 2; ++kk) {
      short8 bK[4];
#pragma unroll
      for (int n = 0; n < 4; ++n) {
        int krow = n * 16 + l15;
        int blk = (kk * 4 + l4) ^ (krow & 7);
        bK[n] = *(const short8*)((const char*)Klds + krow * 128 + blk * 16);
      }
#pragma unroll
      for (int m = 0; m < 2; ++m)
#pragma unroll
        for (int n = 0; n < 4; ++n)
          sc[m][n] = __builtin_amdgcn_mfma_f32_16x16x32_bf16(aQ[m][kk], bK[n], sc[m][n], 0, 0, 0);
    }
    // online softmax (rows live in 16-lane groups)
    float pvv[2][4][4];
#pragma unroll
    for (int m = 0; m < 2; ++m)
#pragma unroll
      for (int r = 0; r < 4; ++r) {
        float mx = -1e30f;
#pragma unroll
        for (int n = 0; n < 4; ++n) { sc[m][n][r] *= 0.125f; mx = fmaxf(mx, sc[m][n][r]); }
#pragma unroll
        for (int o = 1; o < 16; o <<= 1) mx = fmaxf(mx, __shfl_xor(mx, o));
        float mn = fmaxf(mrun[m][r], mx);
        float corr = __expf(mrun[m][r] - mn);
        mrun[m][r] = mn;
        float rsum = 0.f;
#pragma unroll
        for (int n = 0; n < 4; ++n) {
          float p = __expf(sc[m][n][r] - mn);
          pvv[m][n][r] = p; rsum += p;
        }
#pragma unroll
        for (int o = 1; o < 16; o <<= 1) rsum += __shfl_xor(rsum, o);
        lrun[m][r] = lrun[m][r] * corr + rsum;
#pragma unroll
        for (int n = 0; n < 4; ++n) accO[m][n][r] *= corr;
      }
    // P -> LDS (bf16, swizzled), wave-private region
#pragma unroll
    for (int m = 0; m < 2; ++m)
#pragma unroll
      for (int n = 0; n < 4; ++n)
#pragma unroll
        for (int r = 0; r < 4; ++r) {
          int prow = m * 16 + l4 * 4 + r;
          int pcolb = (n * 16 + l15) * 2;
          *(unsigned short*)((char*)Plds[wid] + prow * 128 + (pcolb ^ ((prow & 7) << 4)))
              = f2bf(pvv[m][n][r]);
        }
    // O += P V
#pragma unroll
    for (int kk = 0; kk < 2; ++kk) {
      short8 aP[2], bV[4];
#pragma unroll
      for (int m = 0; m < 2; ++m) {
        int prow = m * 16 + l15;
        int blk = (kk * 4 + l4) ^ (prow & 7);
        aP[m] = *(const short8*)((const char*)Plds[wid] + prow * 128 + blk * 16);
      }
#pragma unroll
      for (int n = 0; n < 4; ++n) {
        int vrow = n * 16 + l15;
        int blk = (kk * 4 + l4) ^ (vrow & 7);
        bV[n] = *(const short8*)((const char*)Vlds + vrow * 128 + blk * 16);
      }
#pragma unroll
      for (int m = 0; m < 2; ++m)
#pragma unroll
        for (int n = 0; n < 4; ++n)
          accO[m][n] = __builtin_amdgcn_mfma_f32_16x16x32_bf16(aP[m], bV[n], accO[m][n], 0, 0, 0);
    }
    asm volatile("" ::: "memory");
    __builtin_amdgcn_s_barrier();
    asm volatile("" ::: "memory");
  }
  size_t pb = (size_t)(head * NCHUNK + chunk) * 128;
#pragma unroll
  for (int m = 0; m < 2; ++m)
#pragma unroll
    for (int n = 0; n < 4; ++n)
#pragma unroll
      for (int r = 0; r < 4; ++r) {
        int q = wid * 32 + m * 16 + l4 * 4 + r;
        Op[(pb + q) * 64 + n * 16 + l15] = accO[m][n][r];
      }
  if (l15 == 0) {
#pragma unroll
    for (int m = 0; m < 2; ++m)
#pragma unroll
      for (int r = 0; r < 4; ++r) {
        int q = wid * 32 + m * 16 + l4 * 4 + r;
        mp[pb + q] = mrun[m][r];
        lp[pb + q] = lrun[m][r];
      }
  }
}

// ---------------- combine partials + q1 = q0 + 0.5*ctx + LN2 -> h ------
__device__ __forceinline__ float blk_sum256(float v, volatile float* red) {
  int tid = threadIdx.x;
#pragma unroll
  for (int o = 32; o; o >>= 1) v += __shfl_xor(v, o);
  __syncthreads();
  if ((tid & 63) == 0) red[tid >> 6] = v;
  __syncthreads();
  return red[0] + red[1] + red[2] + red[3];
}

__global__ __launch_bounds__(256) void combine_ln2(
    const float* __restrict__ Op, const float* __restrict__ mp, const float* __restrict__ lp,
    const float* __restrict__ q0f, const float* __restrict__ g2, const float* __restrict__ b2,
    float* __restrict__ q1, unsigned short* __restrict__ hb)
{
  int q = blockIdx.x, tid = threadIdx.x;
  __shared__ float mS[HEADS * NCHUNK], lS[HEADS * NCHUNK];
  __shared__ float red[4];
  for (int i = tid; i < HEADS * NCHUNK; i += 256) {
    mS[i] = mp[(size_t)i * 128 + q];
    lS[i] = lp[(size_t)i * 128 + q];
  }
  __syncthreads();
  float vals[3];
#pragma unroll
  for (int ii = 0; ii < 3; ++ii) {
    int c = tid + ii * 256;
    int h = c >> 6, d = c & 63;
    float mt = -1e30f;
    for (int cc = 0; cc < NCHUNK; ++cc) mt = fmaxf(mt, mS[h * NCHUNK + cc]);
    float num = 0.f, den = 0.f;
    for (int cc = 0; cc < NCHUNK; ++cc) {
      float w = __expf(mS[h * NCHUNK + cc] - mt);
      den += w * lS[h * NCHUNK + cc];
      num += w * Op[((size_t)(h * NCHUNK + cc) * 128 + q) * 64 + d];
    }
    float ctx = 0.5f * num / den;
    float v = q0f[(size_t)q * DIM + c] + ctx;
    q1[(size_t)q * DIM + c] = v;
    vals[ii] = v;
  }
  float s = blk_sum256(vals[0] + vals[1] + vals[2], red);
  float mean = s * (1.f / 768.f);
  float d0 = vals[0] - mean, d1 = vals[1] - mean, d2 = vals[2] - mean;
  float ss = blk_sum256(d0 * d0 + d1 * d1 + d2 * d2, red);
  float rs = rsqrtf(ss * (1.f / 768.f) + 1e-5f);
#pragma unroll
  for (int ii = 0; ii < 3; ++ii) {
    int c = tid + ii * 256;
    hb[(size_t)q * DIM + c] = f2bf((vals[ii] - mean) * rs * g2[c] + b2[c]);
  }
}

// ------------------------------- host -----------------------------------
extern "C" void kernel_launch(void* const* d_in, const int* in_sizes, int n_in,
                              void* d_out, int out_size, void* d_ws, size_t ws_size,
                              hipStream_t stream) {
  const float* x   = (const float*)d_in[0];
  const float* cls = (const float*)d_in[1];
  const float* g1  = (const float*)d_in[2];
  const float* b1  = (const float*)d_in[3];
  const float* g2  = (const float*)d_in[4];
  const float* b2  = (const float*)d_in[5];
  const float* Wq  = (const float*)d_in[6];
  const float* Wk  = (const float*)d_in[7];
  const float* Wv  = (const float*)d_in[8];
  const float* fcw = (const float*)d_in[13];
  const float* fcb = (const float*)d_in[14];
  const float* pw  = (const float*)d_in[15];
  const float* pb  = (const float*)d_in[16];

  char* ws = (char*)d_ws;
  size_t off = 0;
  auto alloc = [&](size_t bytes) {
    char* p = ws + off;
    off += (bytes + 255) & ~(size_t)255;
    return p;
  };
  unsigned short* xxb  = (unsigned short*)alloc((size_t)ROWS_ALL * DIM * 2);
  float*          q0f  = (float*)alloc((size_t)NB * DIM * 4);
  unsigned short* Kbf  = (unsigned short*)alloc((size_t)ROWS_KV * DIM * 2);
  unsigned short* Vtb  = (unsigned short*)alloc((size_t)DIM * ROWS_KV * 2);
  unsigned short* Qbf  = (unsigned short*)alloc((size_t)NB * DIM * 2);
  unsigned short* wpk  = (unsigned short*)alloc((size_t)5 * DIM * DIM * 2);
  float*          Opar = (float*)alloc((size_t)HEADS * NCHUNK * 128 * 64 * 4);
  float*          mpar = (float*)alloc((size_t)HEADS * NCHUNK * 128 * 4);
  float*          lpar = (float*)alloc((size_t)HEADS * NCHUNK * 128 * 4);
  float*          q1   = (float*)alloc((size_t)NB * DIM * 4);
  unsigned short* hb   = (unsigned short*)alloc((size_t)NB * DIM * 2);
  unsigned short* m1b  = (unsigned short*)alloc((size_t)NB * DIM * 2);

  unsigned short* Wqb = wpk;
  unsigned short* Wkb = wpk + (size_t)1 * DIM * DIM;
  unsigned short* Wvb = wpk + (size_t)2 * DIM * DIM;
  unsigned short* fwb = wpk + (size_t)3 * DIM * DIM;
  unsigned short* pwb = wpk + (size_t)4 * DIM * DIM;

  ln1_kernel<<<ROWS_ALL / 4, 256, 0, stream>>>(x, cls, g1, b1, xxb, q0f);
  castw5<<<dim3(DIM * DIM / 4 / 256, 5), 256, 0, stream>>>(Wq, Wk, Wv, fcw, pw, wpk);

  // K = xx_kv @ Wk^T       (row-major [key][768])
  gemm_bt<0><<<dim3(DIM / 128, ROWS_KV / 128), 256, 0, stream>>>(
      xxb + (size_t)NB * DIM, Wkb, Kbf, ROWS_KV, DIM, DIM, nullptr, nullptr);
  // V^T = Wv @ xx_kv^T     (row-major [d][key])
  gemm_bt<0><<<dim3(ROWS_KV / 128, DIM / 128), 256, 0, stream>>>(
      Wvb, xxb + (size_t)NB * DIM, Vtb, DIM, ROWS_KV, DIM, nullptr, nullptr);
  // Q = q0_ln @ Wq^T
  gemm_bt<0><<<dim3(DIM / 128, 1), 256, 0, stream>>>(
      xxb, Wqb, Qbf, NB, DIM, DIM, nullptr, nullptr);

  attn_partial<<<HEADS * NCHUNK, 256, 0, stream>>>(Qbf, Kbf, Vtb, Opar, mpar, lpar);
  combine_ln2<<<NB, 256, 0, stream>>>(Opar, mpar, lpar, q0f, g2, b2, q1, hb);

  // m1 = silu(h @ fc_w^T + fc_b)
  gemm_bt<1><<<dim3(DIM / 128, 1), 256, 0, stream>>>(
      hb, fwb, m1b, NB, DIM, DIM, fcb, nullptr);
  // out = q1 + m1 @ proj_w^T + proj_b
  gemm_bt<2><<<dim3(DIM / 128, 1), 256, 0, stream>>>(
      m1b, pwb, d_out, NB, DIM, DIM, pb, q1);
}

// Round 2
// 220.911 us; speedup vs baseline: 1.0948x; 1.0948x over previous
//
#include <hip/hip_runtime.h>

#define DIM 768
#define HEADS 12
#define HD 64
#define NB 128
#define ROWS_ALL 25216   // 197*128
#define ROWS_KV  25088   // 196*128
#define NCHUNK 49
#define CKEYS 512        // keys per chunk (49*512 = 25088)

typedef __attribute__((ext_vector_type(8))) short short8;
typedef __attribute__((ext_vector_type(4))) float f32x4;

__device__ __forceinline__ unsigned short f2bf(float f) {
  union { float f; unsigned u; } a; a.f = f;
  return (unsigned short)((a.u + 0x7fffu + ((a.u >> 16) & 1u)) >> 16);
}

__device__ __forceinline__ void gload16(const void* g, void* l) {
  __builtin_amdgcn_global_load_lds(
      (__attribute__((address_space(1))) void*)g,
      (__attribute__((address_space(3))) void*)l, 16, 0, 0);
}

// ---------------- LN1 over concat([cls, x]) -> bf16 xx, plus fp32 q0 ----
__global__ __launch_bounds__(256) void ln1_kernel(
    const float* __restrict__ x, const float* __restrict__ cls,
    const float* __restrict__ g, const float* __restrict__ b,
    unsigned short* __restrict__ xx, float* __restrict__ q0f)
{
  int row = blockIdx.x * 4 + (threadIdx.x >> 6);
  int lane = threadIdx.x & 63;
  const float* src = (row < NB) ? (cls + (size_t)row * DIM)
                                : (x + (size_t)(row - NB) * DIM);
  float4 v[3];
  float s = 0.f;
#pragma unroll
  for (int i = 0; i < 3; ++i) {
    v[i] = ((const float4*)src)[lane + 64 * i];
    s += v[i].x + v[i].y + v[i].z + v[i].w;
  }
#pragma unroll
  for (int o = 32; o; o >>= 1) s += __shfl_xor(s, o);
  float mean = s * (1.f / 768.f);
  float ss = 0.f;
#pragma unroll
  for (int i = 0; i < 3; ++i) {
    float a0 = v[i].x - mean, a1 = v[i].y - mean, a2 = v[i].z - mean, a3 = v[i].w - mean;
    ss += a0 * a0 + a1 * a1 + a2 * a2 + a3 * a3;
  }
#pragma unroll
  for (int o = 32; o; o >>= 1) ss += __shfl_xor(ss, o);
  float rs = rsqrtf(ss * (1.f / 768.f) + 1e-5f);
#pragma unroll
  for (int i = 0; i < 3; ++i) {
    int c4 = lane + 64 * i;
    float4 gv = ((const float4*)g)[c4];
    float4 bv = ((const float4*)b)[c4];
    float o0 = (v[i].x - mean) * rs * gv.x + bv.x;
    float o1 = (v[i].y - mean) * rs * gv.y + bv.y;
    float o2 = (v[i].z - mean) * rs * gv.z + bv.z;
    float o3 = (v[i].w - mean) * rs * gv.w + bv.w;
    ushort4 u; u.x = f2bf(o0); u.y = f2bf(o1); u.z = f2bf(o2); u.w = f2bf(o3);
    ((ushort4*)(xx + (size_t)row * DIM))[c4] = u;
    if (row < NB) {
      float4 fo; fo.x = o0; fo.y = o1; fo.z = o2; fo.w = o3;
      ((float4*)(q0f + (size_t)row * DIM))[c4] = fo;
    }
  }
}

// ---------------- cast 5 weight matrices f32 -> bf16 (packed dst) -------
__global__ __launch_bounds__(256) void castw5(
    const float* __restrict__ s0, const float* __restrict__ s1,
    const float* __restrict__ s2, const float* __restrict__ s3,
    const float* __restrict__ s4, unsigned short* __restrict__ dst)
{
  const float* srcs[5] = { s0, s1, s2, s3, s4 };
  int w = blockIdx.y;
  const float* s = srcs[w];
  unsigned short* d = dst + (size_t)w * (DIM * DIM);
  int i = blockIdx.x * 256 + threadIdx.x;            // float4 index
  float4 v = ((const float4*)s)[i];
  ushort4 u; u.x = f2bf(v.x); u.y = f2bf(v.y); u.z = f2bf(v.z); u.w = f2bf(v.w);
  ((ushort4*)d)[i] = u;
}

// ------- C[m][n] = sum_k A[m][k]*Bt[n][k], BM=BN=128, BK=64, swizzled ---
// EPI 0: bf16 store; 1: +bias, silu(1.702), bf16 store; 2: +bias +addsrc, f32 store
// MAPT 0: consecutive swz blocks share A row-panel; 1: share Bt row-panel
template <int EPI, int MAPT>
__global__ __launch_bounds__(256, 2) void gemm_bt64(
    const unsigned short* __restrict__ A, const unsigned short* __restrict__ Bt,
    void* __restrict__ Cout, int M, int N, int K,
    const float* __restrict__ bias, const float* __restrict__ addsrc)
{
  __shared__ unsigned short Asm[2][128 * 64];   // 16KB x2
  __shared__ unsigned short Bsm[2][128 * 64];   // 16KB x2
  int tid = threadIdx.x, wid = tid >> 6, lane = tid & 63;
  int l15 = lane & 15, l4 = lane >> 4;

  // bijective XCD-chunk swizzle (m204)
  int nwg = gridDim.x * gridDim.y;
  int bid = blockIdx.y * gridDim.x + blockIdx.x;
  int qq = nwg >> 3, r8 = nwg & 7;
  int xcd = bid & 7, rank = bid >> 3;
  int swz = (xcd < r8 ? xcd * (qq + 1) : r8 * (qq + 1) + (xcd - r8) * qq) + rank;
  int bx, by;
  if (MAPT) { by = swz % gridDim.y; bx = swz / gridDim.y; }
  else      { bx = swz % gridDim.x; by = swz / gridDim.x; }
  int row0 = by * 128, col0 = bx * 128;

  // staging: each pass covers 32 rows; row = p*32 + (tid>>3), blk = tid&7
  // pre-swizzled source column block: (tid&7) ^ (row&7); (row&7)==((tid>>3)&7)
  int srow = tid >> 3;
  int scol = ((tid & 7) ^ (srow & 7)) << 4;
  const char* Ag = (const char*)A + (size_t)(row0 + srow) * K * 2 + scol;
  const char* Bg = (const char*)Bt + (size_t)(col0 + srow) * K * 2 + scol;
  size_t rstep32 = (size_t)32 * K * 2;

#define STAGE(buf, kt) do {                                           \
    const char* a0 = Ag + (size_t)(kt) * 128;                         \
    const char* b0 = Bg + (size_t)(kt) * 128;                         \
    char* la = (char*)Asm[buf] + wid * 1024;                          \
    char* lb = (char*)Bsm[buf] + wid * 1024;                          \
    gload16(a0,                la);                                   \
    gload16(a0 + rstep32,      la + 4096);                            \
    gload16(a0 + 2 * rstep32,  la + 8192);                            \
    gload16(a0 + 3 * rstep32,  la + 12288);                           \
    gload16(b0,                lb);                                   \
    gload16(b0 + rstep32,      lb + 4096);                            \
    gload16(b0 + 2 * rstep32,  lb + 8192);                            \
    gload16(b0 + 3 * rstep32,  lb + 12288);                           \
  } while (0)

  f32x4 acc[4][4] = {};
  int wr = (wid >> 1) * 64, wc = (wid & 1) * 64;
  int nk = K >> 6;                 // BK=64
  STAGE(0, 0);
  for (int t = 0; t < nk; ++t) {
    int cur = t & 1;
    if (t + 1 < nk) {
      STAGE(cur ^ 1, t + 1);
      asm volatile("s_waitcnt vmcnt(8)" ::: "memory");
    } else {
      asm volatile("s_waitcnt vmcnt(0)" ::: "memory");
    }
    __builtin_amdgcn_s_barrier();
    asm volatile("" ::: "memory");
    short8 aF[4][2], bF[4][2];
    const char* Ab = (const char*)Asm[cur];
    const char* Bb = (const char*)Bsm[cur];
#pragma unroll
    for (int m = 0; m < 4; ++m) {
      int row = wr + m * 16 + l15;
#pragma unroll
      for (int kk = 0; kk < 2; ++kk)
        aF[m][kk] = *(const short8*)(Ab + row * 128 + ((((kk << 2) | l4) ^ (row & 7)) << 4));
    }
#pragma unroll
    for (int n = 0; n < 4; ++n) {
      int row = wc + n * 16 + l15;
#pragma unroll
      for (int kk = 0; kk < 2; ++kk)
        bF[n][kk] = *(const short8*)(Bb + row * 128 + ((((kk << 2) | l4) ^ (row & 7)) << 4));
    }
#pragma unroll
    for (int kk = 0; kk < 2; ++kk)
#pragma unroll
      for (int m = 0; m < 4; ++m)
#pragma unroll
        for (int n = 0; n < 4; ++n)
          acc[m][n] = __builtin_amdgcn_mfma_f32_16x16x32_bf16(aF[m][kk], bF[n][kk], acc[m][n], 0, 0, 0);
    asm volatile("" ::: "memory");
    __builtin_amdgcn_s_barrier();
    asm volatile("" ::: "memory");
  }
#undef STAGE
#pragma unroll
  for (int m = 0; m < 4; ++m)
#pragma unroll
    for (int n = 0; n < 4; ++n)
#pragma unroll
      for (int r = 0; r < 4; ++r) {
        int rr = row0 + wr + m * 16 + l4 * 4 + r;
        int cc = col0 + wc + n * 16 + l15;
        float v = acc[m][n][r];
        if (EPI == 0) {
          ((unsigned short*)Cout)[(size_t)rr * N + cc] = f2bf(v);
        } else if (EPI == 1) {
          v += bias[cc];
          v = v / (1.f + __expf(-1.702f * v));
          ((unsigned short*)Cout)[(size_t)rr * N + cc] = f2bf(v);
        } else {
          v += bias[cc] + addsrc[(size_t)rr * N + cc];
          ((float*)Cout)[(size_t)rr * N + cc] = v;
        }
      }
}

// ---------------- flash-decode attention partials (double-buffered) -----
// block = (head, chunk); 4 waves x 32 queries; 8 key-tiles of 64
__global__ __launch_bounds__(256) void attn_partial(
    const unsigned short* __restrict__ Qb, const unsigned short* __restrict__ Kb,
    const unsigned short* __restrict__ Vt,
    float* __restrict__ Op, float* __restrict__ mp, float* __restrict__ lp)
{
  __shared__ unsigned short Klds[2][64 * 64];
  __shared__ unsigned short Vlds[2][64 * 64];
  __shared__ unsigned short Plds[4][32 * 64];
  int tid = threadIdx.x, wid = tid >> 6, lane = tid & 63;
  int l15 = lane & 15, l4 = lane >> 4;
  int head = blockIdx.x / NCHUNK, chunk = blockIdx.x % NCHUNK;

  short8 aQ[2][2];
#pragma unroll
  for (int m = 0; m < 2; ++m)
#pragma unroll
    for (int kk = 0; kk < 2; ++kk) {
      int qrow = wid * 32 + m * 16 + l15;
      aQ[m][kk] = *(const short8*)(Qb + (size_t)qrow * DIM + head * HD + kk * 32 + l4 * 8);
    }
  f32x4 accO[2][4] = {};
  float mrun[2][4], lrun[2][4];
#pragma unroll
  for (int m = 0; m < 2; ++m)
#pragma unroll
    for (int r = 0; r < 4; ++r) { mrun[m][r] = -1e30f; lrun[m][r] = 0.f; }

  // staging addresses: per-lane pre-swizzled global source, linear LDS dest
  int srow = tid >> 3;                       // 0..31 within a 32-row pass
  int sblk = (tid & 7) ^ (srow & 7);
  const char* Kg = (const char*)(Kb + (size_t)(chunk * CKEYS + srow) * DIM + head * HD) + sblk * 16;
  const char* Vg = (const char*)(Vt + (size_t)(head * HD + srow) * ROWS_KV + chunk * CKEYS) + sblk * 16;

#define STAGEKV(buf, kt) do {                                         \
    const char* k0 = Kg + (size_t)(kt) * 64 * DIM * 2;                \
    const char* v0 = Vg + (size_t)(kt) * 128;                         \
    char* lk = (char*)Klds[buf] + wid * 1024;                         \
    char* lv = (char*)Vlds[buf] + wid * 1024;                         \
    gload16(k0,                        lk);                           \
    gload16(k0 + (size_t)32 * DIM * 2, lk + 4096);                    \
    gload16(v0,                        lv);                           \
    gload16(v0 + (size_t)32 * ROWS_KV * 2, lv + 4096);                \
  } while (0)

  STAGEKV(0, 0);
  for (int kt = 0; kt < 8; ++kt) {
    int cur = kt & 1;
    if (kt + 1 < 8) {
      STAGEKV(cur ^ 1, kt + 1);
      asm volatile("s_waitcnt vmcnt(4)" ::: "memory");
    } else {
      asm volatile("s_waitcnt vmcnt(0)" ::: "memory");
    }
    __builtin_amdgcn_s_barrier();
    asm volatile("" ::: "memory");

    // S = Q K^T
    f32x4 sc[2][4] = {};
    __builtin_amdgcn_s_setprio(1);
#pragma unroll
    for (int kk = 0; kk < 2; ++kk) {
      short8 bK[4];
#pragma unroll
      for (int n = 0; n < 4; ++n) {
        int krow = n * 16 + l15;
        int blk = (kk * 4 + l4) ^ (krow & 7);
        bK[n] = *(const short8*)((const char*)Klds[cur] + krow * 128 + blk * 16);
      }
#pragma unroll
      for (int m = 0; m < 2; ++m)
#pragma unroll
        for (int n = 0; n < 4; ++n)
          sc[m][n] = __builtin_amdgcn_mfma_f32_16x16x32_bf16(aQ[m][kk], bK[n], sc[m][n], 0, 0, 0);
    }
    __builtin_amdgcn_s_setprio(0);
    // online softmax (rows live in 16-lane groups)
    float pvv[2][4][4];
#pragma unroll
    for (int m = 0; m < 2; ++m)
#pragma unroll
      for (int r = 0; r < 4; ++r) {
        float mx = -1e30f;
#pragma unroll
        for (int n = 0; n < 4; ++n) { sc[m][n][r] *= 0.125f; mx = fmaxf(mx, sc[m][n][r]); }
#pragma unroll
        for (int o = 1; o < 16; o <<= 1) mx = fmaxf(mx, __shfl_xor(mx, o));
        float mn = fmaxf(mrun[m][r], mx);
        float corr = __expf(mrun[m][r] - mn);
        mrun[m][r] = mn;
        float rsum = 0.f;
#pragma unroll
        for (int n = 0; n < 4; ++n) {
          float p = __expf(sc[m][n][r] - mn);
          pvv[m][n][r] = p; rsum += p;
        }
#pragma unroll
        for (int o = 1; o < 16; o <<= 1) rsum += __shfl_xor(rsum, o);
        lrun[m][r] = lrun[m][r] * corr + rsum;
#pragma unroll
        for (int n = 0; n < 4; ++n) accO[m][n][r] *= corr;
      }
    // P -> LDS (bf16, swizzled), wave-private region
#pragma unroll
    for (int m = 0; m < 2; ++m)
#pragma unroll
      for (int n = 0; n < 4; ++n)
#pragma unroll
        for (int r = 0; r < 4; ++r) {
          int prow = m * 16 + l4 * 4 + r;
          int pcolb = (n * 16 + l15) * 2;
          *(unsigned short*)((char*)Plds[wid] + prow * 128 + (pcolb ^ ((prow & 7) << 4)))
              = f2bf(pvv[m][n][r]);
        }
    // O += P V
    __builtin_amdgcn_s_setprio(1);
#pragma unroll
    for (int kk = 0; kk < 2; ++kk) {
      short8 aP[2], bV[4];
#pragma unroll
      for (int m = 0; m < 2; ++m) {
        int prow = m * 16 + l15;
        int blk = (kk * 4 + l4) ^ (prow & 7);
        aP[m] = *(const short8*)((const char*)Plds[wid] + prow * 128 + blk * 16);
      }
#pragma unroll
      for (int n = 0; n < 4; ++n) {
        int vrow = n * 16 + l15;
        int blk = (kk * 4 + l4) ^ (vrow & 7);
        bV[n] = *(const short8*)((const char*)Vlds[cur] + vrow * 128 + blk * 16);
      }
#pragma unroll
      for (int m = 0; m < 2; ++m)
#pragma unroll
        for (int n = 0; n < 4; ++n)
          accO[m][n] = __builtin_amdgcn_mfma_f32_16x16x32_bf16(aP[m], bV[n], accO[m][n], 0, 0, 0);
    }
    __builtin_amdgcn_s_setprio(0);
    asm volatile("" ::: "memory");
    __builtin_amdgcn_s_barrier();
    asm volatile("" ::: "memory");
  }
#undef STAGEKV
  size_t pb = (size_t)(head * NCHUNK + chunk) * 128;
#pragma unroll
  for (int m = 0; m < 2; ++m)
#pragma unroll
    for (int n = 0; n < 4; ++n)
#pragma unroll
      for (int r = 0; r < 4; ++r) {
        int q = wid * 32 + m * 16 + l4 * 4 + r;
        Op[(pb + q) * 64 + n * 16 + l15] = accO[m][n][r];
      }
  if (l15 == 0) {
#pragma unroll
    for (int m = 0; m < 2; ++m)
#pragma unroll
      for (int r = 0; r < 4; ++r) {
        int q = wid * 32 + m * 16 + l4 * 4 + r;
        mp[pb + q] = mrun[m][r];
        lp[pb + q] = lrun[m][r];
      }
  }
}

// ---------------- combine partials + q1 = q0 + 0.5*ctx + LN2 -> h ------
__device__ __forceinline__ float blk_sum256(float v, volatile float* red) {
  int tid = threadIdx.x;
#pragma unroll
  for (int o = 32; o; o >>= 1) v += __shfl_xor(v, o);
  __syncthreads();
  if ((tid & 63) == 0) red[tid >> 6] = v;
  __syncthreads();
  return red[0] + red[1] + red[2] + red[3];
}

__global__ __launch_bounds__(256) void combine_ln2(
    const float* __restrict__ Op, const float* __restrict__ mp, const float* __restrict__ lp,
    const float* __restrict__ q0f, const float* __restrict__ g2, const float* __restrict__ b2,
    float* __restrict__ q1, unsigned short* __restrict__ hb)
{
  int q = blockIdx.x, tid = threadIdx.x;
  __shared__ float mS[HEADS * NCHUNK], lS[HEADS * NCHUNK];
  __shared__ float red[4];
  for (int i = tid; i < HEADS * NCHUNK; i += 256) {
    mS[i] = mp[(size_t)i * 128 + q];
    lS[i] = lp[(size_t)i * 128 + q];
  }
  __syncthreads();
  float vals[3];
#pragma unroll
  for (int ii = 0; ii < 3; ++ii) {
    int c = tid + ii * 256;
    int h = c >> 6, d = c & 63;
    float mt = -1e30f;
    for (int cc = 0; cc < NCHUNK; ++cc) mt = fmaxf(mt, mS[h * NCHUNK + cc]);
    float num = 0.f, den = 0.f;
    for (int cc = 0; cc < NCHUNK; ++cc) {
      float w = __expf(mS[h * NCHUNK + cc] - mt);
      den += w * lS[h * NCHUNK + cc];
      num += w * Op[((size_t)(h * NCHUNK + cc) * 128 + q) * 64 + d];
    }
    float ctx = 0.5f * num / den;
    float v = q0f[(size_t)q * DIM + c] + ctx;
    q1[(size_t)q * DIM + c] = v;
    vals[ii] = v;
  }
  float s = blk_sum256(vals[0] + vals[1] + vals[2], red);
  float mean = s * (1.f / 768.f);
  float d0 = vals[0] - mean, d1 = vals[1] - mean, d2 = vals[2] - mean;
  float ss = blk_sum256(d0 * d0 + d1 * d1 + d2 * d2, red);
  float rs = rsqrtf(ss * (1.f / 768.f) + 1e-5f);
#pragma unroll
  for (int ii = 0; ii < 3; ++ii) {
    int c = tid + ii * 256;
    hb[(size_t)q * DIM + c] = f2bf((vals[ii] - mean) * rs * g2[c] + b2[c]);
  }
}

// ------------------------------- host -----------------------------------
extern "C" void kernel_launch(void* const* d_in, const int* in_sizes, int n_in,
                              void* d_out, int out_size, void* d_ws, size_t ws_size,
                              hipStream_t stream) {
  const float* x   = (const float*)d_in[0];
  const float* cls = (const float*)d_in[1];
  const float* g1  = (const float*)d_in[2];
  const float* b1  = (const float*)d_in[3];
  const float* g2  = (const float*)d_in[4];
  const float* b2  = (const float*)d_in[5];
  const float* Wq  = (const float*)d_in[6];
  const float* Wk  = (const float*)d_in[7];
  const float* Wv  = (const float*)d_in[8];
  const float* fcw = (const float*)d_in[13];
  const float* fcb = (const float*)d_in[14];
  const float* pw  = (const float*)d_in[15];
  const float* pb  = (const float*)d_in[16];

  char* ws = (char*)d_ws;
  size_t off = 0;
  auto alloc = [&](size_t bytes) {
    char* p = ws + off;
    off += (bytes + 255) & ~(size_t)255;
    return p;
  };
  unsigned short* xxb  = (unsigned short*)alloc((size_t)ROWS_ALL * DIM * 2);
  float*          q0f  = (float*)alloc((size_t)NB * DIM * 4);
  unsigned short* Kbf  = (unsigned short*)alloc((size_t)ROWS_KV * DIM * 2);
  unsigned short* Vtb  = (unsigned short*)alloc((size_t)DIM * ROWS_KV * 2);
  unsigned short* Qbf  = (unsigned short*)alloc((size_t)NB * DIM * 2);
  unsigned short* wpk  = (unsigned short*)alloc((size_t)5 * DIM * DIM * 2);
  float*          Opar = (float*)alloc((size_t)HEADS * NCHUNK * 128 * 64 * 4);
  float*          mpar = (float*)alloc((size_t)HEADS * NCHUNK * 128 * 4);
  float*          lpar = (float*)alloc((size_t)HEADS * NCHUNK * 128 * 4);
  float*          q1   = (float*)alloc((size_t)NB * DIM * 4);
  unsigned short* hb   = (unsigned short*)alloc((size_t)NB * DIM * 2);
  unsigned short* m1b  = (unsigned short*)alloc((size_t)NB * DIM * 2);

  unsigned short* Wqb = wpk;
  unsigned short* Wkb = wpk + (size_t)1 * DIM * DIM;
  unsigned short* Wvb = wpk + (size_t)2 * DIM * DIM;
  unsigned short* fwb = wpk + (size_t)3 * DIM * DIM;
  unsigned short* pwb = wpk + (size_t)4 * DIM * DIM;

  ln1_kernel<<<ROWS_ALL / 4, 256, 0, stream>>>(x, cls, g1, b1, xxb, q0f);
  castw5<<<dim3(DIM * DIM / 4 / 256, 5), 256, 0, stream>>>(Wq, Wk, Wv, fcw, pw, wpk);

  // K = xx_kv @ Wk^T       (row-major [key][768]); big operand = A rows
  gemm_bt64<0, 0><<<dim3(DIM / 128, ROWS_KV / 128), 256, 0, stream>>>(
      xxb + (size_t)NB * DIM, Wkb, Kbf, ROWS_KV, DIM, DIM, nullptr, nullptr);
  // V^T = Wv @ xx_kv^T     (row-major [d][key]); big operand = Bt rows
  gemm_bt64<0, 1><<<dim3(ROWS_KV / 128, DIM / 128), 256, 0, stream>>>(
      Wvb, xxb + (size_t)NB * DIM, Vtb, DIM, ROWS_KV, DIM, nullptr, nullptr);
  // Q = q0_ln @ Wq^T
  gemm_bt64<0, 0><<<dim3(DIM / 128, 1), 256, 0, stream>>>(
      xxb, Wqb, Qbf, NB, DIM, DIM, nullptr, nullptr);

  attn_partial<<<HEADS * NCHUNK, 256, 0, stream>>>(Qbf, Kbf, Vtb, Opar, mpar, lpar);
  combine_ln2<<<NB, 256, 0, stream>>>(Opar, mpar, lpar, q0f, g2, b2, q1, hb);

  // m1 = silu(h @ fc_w^T + fc_b)
  gemm_bt64<1, 0><<<dim3(DIM / 128, 1), 256, 0, stream>>>(
      hb, fwb, m1b, NB, DIM, DIM, fcb, nullptr);
  // out = q1 + m1 @ proj_w^T + proj_b
  gemm_bt64<2, 0><<<dim3(DIM / 128, 1), 256, 0, stream>>>(
      m1b, pwb, d_out, NB, DIM, DIM, pb, q1);
}